// Round 10
// baseline (143.342 us; speedup 1.0000x reference)
//
#include <hip/hip_runtime.h>

#define B 64
#define N 1024
#define E 16384
#define WPR 32          // words per adjacency row = N/32
#define NITER 5

// ---- workspace layout (bytes) ---- (NO memset: every region fully stored
// before any read; harness 0xAA poison harmless)
#define ADJ_OFF   0
#define ADJ_BYTES ((size_t)B * N * WPR * 4)
#define FEATS_OFF ADJ_BYTES
#define DIAG_OFF  (FEATS_OFF + (size_t)B * N * 4)

// Bit adjacency built in LDS, full rows STORED to global (stores-only => safe
// against workspace poison). R5-R9 measured ~9us.
__global__ void __launch_bounds__(1024) build_adj_k(const int* __restrict__ src,
                                                    const int* __restrict__ dst,
                                                    unsigned int* __restrict__ adj) {
    __shared__ unsigned int s_adj[512 * WPR];       // 64 KiB: 512 rows
    int t = threadIdx.x;
    int b = blockIdx.x >> 1;
    int half = blockIdx.x & 1;
    int row_base = half << 9;

    uint4* s4 = (uint4*)s_adj;
#pragma unroll
    for (int k = 0; k < 4; ++k) s4[t + k * 1024] = make_uint4(0, 0, 0, 0);
    __syncthreads();

    const int* sg = src + (size_t)b * E;
    const int* dg = dst + (size_t)b * E;
#pragma unroll
    for (int k = 0; k < 16; ++k) {
        int e = t + k * 1024;
        int s = sg[e];
        int d = dg[e];
        int r = s - row_base;
        if ((unsigned)r < 512u)
            atomicOr(&s_adj[r * WPR + (d >> 5)], 1u << (d & 31));  // idempotent dedup
    }
    __syncthreads();

    uint4* g4 = (uint4*)(adj + ((size_t)b * N + row_base) * WPR);
#pragma unroll
    for (int k = 0; k < 4; ++k) g4[t + k * 1024] = s4[t + k * 1024];
}

// Whole WL loop, one block per graph, LDS-resident. R10: 9 barriers/iter
// (was 12), no serial w0 sections in the loop (leader LDS atomicMin/Max for
// min/max; broadcast-read wave-prefix for both scans), un-padded CSR
// (R9 falsified the padding theory: conflicts are from random-address
// gathers, not layout stride), diag fused at the end.
__global__ void __launch_bounds__(1024) wl_mega_k(const unsigned int* __restrict__ adj,
                                                  const int* __restrict__ lab0,
                                                  const float* __restrict__ hw,
                                                  unsigned int* __restrict__ feats,
                                                  float* __restrict__ diag) {
    __shared__ unsigned short s_nbr[E];             // 32 KB compact CSR
    __shared__ int s_lab[N];
    __shared__ int s_hist[N];
    __shared__ int s_scan[N];
    __shared__ unsigned int s_grp[N];
    __shared__ int s_flag[N];
    __shared__ unsigned int s_feats[N];
    __shared__ int s_wsum[16];
    __shared__ int s_kp[16];
    __shared__ unsigned int s_gmn, s_gmx;
    int b = blockIdx.x, t = threadIdx.x;
    int lane = t & 63, w = t >> 6;

    // ---- Phase A: row -> deg/CSR/K, init labels + bincount ----
    uint4 r[8];
    const uint4* rowg = (const uint4*)(adj + ((size_t)b * N + t) * WPR);
#pragma unroll
    for (int k = 0; k < 8; ++k) r[k] = rowg[k];
    int dg = 0;
#pragma unroll
    for (int k = 0; k < 8; ++k)
        dg += __popc(r[k].x) + __popc(r[k].y) + __popc(r[k].z) + __popc(r[k].w);

    int f = dg;                                     // wave inclusive scan of deg
#pragma unroll
    for (int d2 = 1; d2 < 64; d2 <<= 1) {
        int v = __shfl_up(f, d2);
        if (lane >= d2) f += v;
    }
    int km = dg;
#pragma unroll
    for (int o = 32; o > 0; o >>= 1) km = max(km, __shfl_down(km, o));
    if (lane == 63) s_wsum[w] = f;
    if (lane == 0)  s_kp[w] = km;

    int l0 = lab0[(size_t)b * N + t];
    s_lab[t] = l0;
    s_feats[t] = 0;
    s_hist[t] = 0;
    s_flag[t] = 0;
    if (t == 0) { s_gmn = 0xFFFFFFFFu; s_gmx = 0u; }
    __syncthreads();                                        // A1
    int base = 0;                                   // broadcast wave-prefix
    for (int k = 0; k < w; ++k) base += s_wsum[k];
    int start = (f - dg) + base;                    // this node's CSR start
    int Ki = 0;
#pragma unroll
    for (int k = 0; k < 16; ++k) Ki = max(Ki, s_kp[k]);

    // pack own row's set bits ONCE -> u16 neighbor list
    {
        int idx = start;
#pragma unroll
        for (int k = 0; k < 8; ++k) {
            unsigned int wv[4] = { r[k].x, r[k].y, r[k].z, r[k].w };
#pragma unroll
            for (int c2 = 0; c2 < 4; ++c2) {
                unsigned int word = wv[c2];
                int bb = (k * 4 + c2) << 5;
                while (word) {
                    int j = __ffs(word) - 1;
                    word &= word - 1;
                    s_nbr[idx++] = (unsigned short)(bb + j);
                }
            }
        }
    }
    // init label bincount (labels < 16) via ballot
#pragma unroll
    for (int v = 0; v < 16; ++v) {
        unsigned long long m = __ballot(l0 == v);
        if (lane == v) {
            int c = __popcll(m);
            if (c) atomicAdd(&s_feats[v], (unsigned)c);
        }
    }
    float Kf = (float)Ki;
    float w0 = hw[0], w1 = hw[1];
    __syncthreads();                                        // A2

    // ---- Phase B: 5 WL iterations, 9 barriers each ----
    for (int it = 0; it < NITER; ++it) {
        // seg gather + exact-_rn hash (bitwise == numpy) -> monotone uint key
        int s = 0;
#pragma unroll 4
        for (int k = 0; k < dg; ++k) s += s_lab[s_nbr[start + k]];
        float t1 = __fmul_rn(__fmul_rn(Kf, w0), (float)s_lab[t]);
        float t2 = __fmul_rn(w1, __fsub_rn(__fadd_rn((float)s, (float)dg), Kf));
        float h  = __fadd_rn(t1, t2);
        unsigned int bits = __float_as_uint(h);
        if (bits == 0x80000000u) bits = 0u;         // -0 == +0
        unsigned int ikey = (bits & 0x80000000u) ? ~bits : (bits | 0x80000000u);

        // block min/max of ikey: wave reduce + 16 leader LDS atomics
        unsigned int mn = ikey, mx = ikey;
#pragma unroll
        for (int o = 32; o > 0; o >>= 1) {
            mn = min(mn, (unsigned)__shfl_down((int)mn, o));
            mx = max(mx, (unsigned)__shfl_down((int)mx, o));
        }
        if (lane == 0) { atomicMin(&s_gmn, mn); atomicMax(&s_gmx, mx); }
        __syncthreads();                                    // B1
        unsigned int gmn = s_gmn;
        unsigned int span = s_gmx - gmn;
        float scale = span ? (1023.0f / (float)span) : 0.f;
        int bucket = min((int)((float)(ikey - gmn) * scale), 1023);  // monotone
        int off_in = atomicAdd(&s_hist[bucket], 1);
        __syncthreads();                                    // B2

        // scan1: bucket sizes -> offsets (wave scan + broadcast prefix)
        f = s_hist[t];
#pragma unroll
        for (int d2 = 1; d2 < 64; d2 <<= 1) {
            int v = __shfl_up(f, d2);
            if (lane >= d2) f += v;
        }
        if (lane == 63) s_wsum[w] = f;
        __syncthreads();                                    // B3
        base = 0;
        for (int k = 0; k < w; ++k) base += s_wsum[k];
        s_scan[t] = f + base;
        __syncthreads();                                    // B4

        int bs = s_scan[bucket] - s_hist[bucket];
        int be = s_scan[bucket];
        s_grp[bs + off_in] = ikey;
        __syncthreads();                                    // B5

        int c = bs;                 // lower buckets strictly less (monotone map)
        for (int k = bs; k < be; ++k) c += (s_grp[k] < ikey);
        s_flag[c] = 1;              // class start (same class -> same c)
        s_hist[t] = 0;              // re-zero (last read was pre-B5)
        __syncthreads();                                    // B6

        // scan2: class-start flags -> dense rank
        int f2 = s_flag[t];
#pragma unroll
        for (int d2 = 1; d2 < 64; d2 <<= 1) {
            int v = __shfl_up(f2, d2);
            if (lane >= d2) f2 += v;
        }
        if (lane == 63) s_wsum[w] = f2;
        __syncthreads();                                    // B7
        base = 0;
        for (int k = 0; k < w; ++k) base += s_wsum[k];
        s_scan[t] = f2 + base;
        __syncthreads();                                    // B8

        int rank = s_scan[c] - 1;
        s_lab[t] = rank;
        atomicAdd(&s_feats[rank], 1u);
        s_flag[t] = 0;              // own flag consumed above
        if (t == 0) { s_gmn = 0xFFFFFFFFu; s_gmx = 0u; }
        __syncthreads();                                    // B9
    }

    // feats out + fused diag[b] = dot(f_b, f_b) (int exact)
    unsigned int fv = s_feats[t];
    feats[(size_t)b * N + t] = fv;
    int sq = (int)(fv * fv);
#pragma unroll
    for (int o = 32; o > 0; o >>= 1) sq += __shfl_down(sq, o);
    if (lane == 0) s_wsum[w] = sq;
    __syncthreads();
    if (t == 0) {
        int tot = 0;
#pragma unroll
        for (int k = 0; k < 16; ++k) tot += s_wsum[k];
        diag[b] = (float)tot;
    }
}

// gram+normalize fused: one block per row i; f_i staged in LDS; writes
// normalized kernel value straight to d_out. int dots exact (< 2^31).
__global__ void __launch_bounds__(256) gram_k(const unsigned int* __restrict__ feats,
                                              const float* __restrict__ diag,
                                              float* __restrict__ out) {
    __shared__ unsigned int s_fi[N];
    int i = blockIdx.x, t = threadIdx.x;
    int lane = t & 63, w = t >> 6;
    ((uint4*)s_fi)[t] = ((const uint4*)(feats + (size_t)i * N))[t];
    __syncthreads();
    float di = diag[i];
    for (int jj = 0; jj < 16; ++jj) {
        int j = w * 16 + jj;
        const uint4* fj = (const uint4*)(feats + (size_t)j * N);
        const uint4* fi = (const uint4*)s_fi;
        int s = 0;
#pragma unroll
        for (int k = 0; k < 4; ++k) {
            uint4 vb = fj[lane + k * 64];
            uint4 va = fi[lane + k * 64];
            s += (int)(va.x * vb.x) + (int)(va.y * vb.y)
               + (int)(va.z * vb.z) + (int)(va.w * vb.w);
        }
#pragma unroll
        for (int off = 32; off > 0; off >>= 1) s += __shfl_down(s, off);
        if (lane == 0) out[i * B + j] = (float)s / sqrtf(di * diag[j]);
    }
}

extern "C" void kernel_launch(void* const* d_in, const int* in_sizes, int n_in,
                              void* d_out, int out_size, void* d_ws, size_t ws_size,
                              hipStream_t stream) {
    const int*   esrc = (const int*)d_in[0];
    const int*   edst = (const int*)d_in[1];
    const int*   lab0 = (const int*)d_in[2];
    const float* hw   = (const float*)d_in[3];

    char* ws = (char*)d_ws;
    unsigned int* adj   = (unsigned int*)(ws + ADJ_OFF);
    unsigned int* feats = (unsigned int*)(ws + FEATS_OFF);
    float*        diag  = (float*)(ws + DIAG_OFF);

    build_adj_k<<<B * 2, 1024, 0, stream>>>(esrc, edst, adj);
    wl_mega_k<<<B, 1024, 0, stream>>>(adj, lab0, hw, feats, diag);
    gram_k<<<B, 256, 0, stream>>>(feats, diag, (float*)d_out);
}

// Round 11
// 122.374 us; speedup vs baseline: 1.1713x; 1.1713x over previous
//
#include <hip/hip_runtime.h>

#define B 64
#define N 1024
#define E 16384
#define WPR 32          // words per adjacency row = N/32
#define NITER 5
#define CSR_SLOTS (E + N)   // even-aligned per-node alloc: <=1 pad slot/node

// ---- workspace layout (bytes) ---- (NO memset: every region fully stored
// before any read; harness 0xAA poison harmless)
#define ADJ_OFF   0
#define ADJ_BYTES ((size_t)B * N * WPR * 4)
#define FEATS_OFF ADJ_BYTES
#define DIAG_OFF  (FEATS_OFF + (size_t)B * N * 4)

// Bit adjacency built in LDS, full rows STORED to global (stores-only => safe
// against workspace poison). R5-R10 measured ~9us.
__global__ void __launch_bounds__(1024) build_adj_k(const int* __restrict__ src,
                                                    const int* __restrict__ dst,
                                                    unsigned int* __restrict__ adj) {
    __shared__ unsigned int s_adj[512 * WPR];       // 64 KiB: 512 rows
    int t = threadIdx.x;
    int b = blockIdx.x >> 1;
    int half = blockIdx.x & 1;
    int row_base = half << 9;

    uint4* s4 = (uint4*)s_adj;
#pragma unroll
    for (int k = 0; k < 4; ++k) s4[t + k * 1024] = make_uint4(0, 0, 0, 0);
    __syncthreads();

    const int* sg = src + (size_t)b * E;
    const int* dg = dst + (size_t)b * E;
#pragma unroll
    for (int k = 0; k < 16; ++k) {
        int e = t + k * 1024;
        int s = sg[e];
        int d = dg[e];
        int r = s - row_base;
        if ((unsigned)r < 512u)
            atomicOr(&s_adj[r * WPR + (d >> 5)], 1u << (d & 31));  // idempotent dedup
    }
    __syncthreads();

    uint4* g4 = (uint4*)(adj + ((size_t)b * N + row_base) * WPR);
#pragma unroll
    for (int k = 0; k < 4; ++k) g4[t + k * 1024] = s4[t + k * 1024];
}

// Whole WL loop, one block per graph, LDS-resident. R11 = R7 skeleton
// (measured-best rank machinery: float keys, 12 barriers, serial t==0
// combines) + pair-packed u32 gather (halves hash-phase LDS ops; sentinel
// node N with s_lab[N]=0 pads odd degrees) + ballot init bincount + fused
// diag. R9 falsified CSR padding; R10 falsified w0-combine/atomic-minmax.
__global__ void __launch_bounds__(1024) wl_mega_k(const unsigned int* __restrict__ adj,
                                                  const int* __restrict__ lab0,
                                                  const float* __restrict__ hw,
                                                  unsigned int* __restrict__ feats,
                                                  float* __restrict__ diag) {
    __shared__ unsigned short s_nbr[CSR_SLOTS];     // 34 KB even-aligned CSR
    __shared__ int s_lab[N + 2];                    // +sentinel slot (=0)
    __shared__ int s_hist[N];
    __shared__ int s_scan[N];
    __shared__ float s_grp[N];
    __shared__ int s_flag[N];
    __shared__ unsigned int s_feats[N];
    __shared__ int s_wsum[16];
    __shared__ float s_mn[17], s_mx[17];
    __shared__ int s_K;
    int b = blockIdx.x, t = threadIdx.x;
    int lane = t & 63, w = t >> 6;

    // ---- Phase A: row -> deg/CSR/K, init labels + bincount ----
    uint4 r[8];
    const uint4* rowg = (const uint4*)(adj + ((size_t)b * N + t) * WPR);
#pragma unroll
    for (int k = 0; k < 8; ++k) r[k] = rowg[k];
    int dg = 0;
#pragma unroll
    for (int k = 0; k < 8; ++k)
        dg += __popc(r[k].x) + __popc(r[k].y) + __popc(r[k].z) + __popc(r[k].w);
    int alloc = (dg + 1) & ~1;                      // even per-node CSR alloc

    // wave inclusive scan of alloc + wave max of deg
    int f = alloc;
#pragma unroll
    for (int d2 = 1; d2 < 64; d2 <<= 1) {
        int v = __shfl_up(f, d2);
        if (lane >= d2) f += v;
    }
    int km = dg;
#pragma unroll
    for (int o = 32; o > 0; o >>= 1) km = max(km, __shfl_down(km, o));
    if (lane == 63) s_wsum[w] = f;
    if (lane == 0)  s_scan[w] = km;                 // scratch for K partials

    int l0 = lab0[(size_t)b * N + t];
    s_lab[t] = l0;
    s_feats[t] = 0;
    s_hist[t] = 0;
    s_flag[t] = 0;
    if (t == 0) s_lab[N] = 0;                       // sentinel label
    __syncthreads();                                        // A1
    if (t == 0) {                                   // serial combine (R7-style)
        int run = 0, m = 0;
#pragma unroll
        for (int k = 0; k < 16; ++k) {
            int tmp = s_wsum[k]; s_wsum[k] = run; run += tmp;
            m = max(m, s_scan[k]);
        }
        s_K = m;
    }
    // init label bincount (labels < 16) via ballot
#pragma unroll
    for (int v = 0; v < 16; ++v) {
        unsigned long long m = __ballot(l0 == v);
        if (lane == v) {
            int c = __popcll(m);
            if (c) atomicAdd(&s_feats[v], (unsigned)c);
        }
    }
    __syncthreads();                                        // A2
    int start = (f - alloc) + s_wsum[w];            // even => u32-aligned

    // pack own row's set bits ONCE -> u16 list; pad odd deg with sentinel N
    {
        int idx = start;
#pragma unroll
        for (int k = 0; k < 8; ++k) {
            unsigned int wv[4] = { r[k].x, r[k].y, r[k].z, r[k].w };
#pragma unroll
            for (int c2 = 0; c2 < 4; ++c2) {
                unsigned int word = wv[c2];
                int bb = (k * 4 + c2) << 5;
                while (word) {
                    int j = __ffs(word) - 1;
                    word &= word - 1;
                    s_nbr[idx++] = (unsigned short)(bb + j);
                }
            }
        }
        if (dg & 1) s_nbr[idx] = (unsigned short)N; // sentinel -> adds 0
    }
    float Kf = (float)s_K;
    float w0 = hw[0], w1 = hw[1];
    int pairs = alloc >> 1;
    int pstart = start >> 1;
    __syncthreads();                                        // A3

    // ---- Phase B: 5 WL iterations (R7 rank machinery verbatim) ----
    for (int it = 0; it < NITER; ++it) {
        // seg gather as u32 PAIRS (halved LDS ops) + exact-_rn hash (== numpy)
        int s = 0;
        const unsigned int* nbr32 = (const unsigned int*)s_nbr;
        for (int k = 0; k < pairs; ++k) {
            unsigned int pr = nbr32[pstart + k];
            s += s_lab[pr & 0xFFFFu] + s_lab[pr >> 16];
        }
        float t1 = __fmul_rn(__fmul_rn(Kf, w0), (float)s_lab[t]);
        float t2 = __fmul_rn(w1, __fsub_rn(__fadd_rn((float)s, (float)dg), Kf));
        float h  = __fadd_rn(t1, t2);

        // block min/max
        float mn = h, mx = h;
#pragma unroll
        for (int o = 32; o > 0; o >>= 1) {
            mn = fminf(mn, __shfl_down(mn, o));
            mx = fmaxf(mx, __shfl_down(mx, o));
        }
        if (lane == 0) { s_mn[w] = mn; s_mx[w] = mx; }
        __syncthreads();                                    // B1
        if (t == 0) {
            float a = s_mn[0], c = s_mx[0];
#pragma unroll
            for (int k = 1; k < 16; ++k) { a = fminf(a, s_mn[k]); c = fmaxf(c, s_mx[k]); }
            s_mn[16] = a; s_mx[16] = c;
        }
        __syncthreads();                                    // B2
        float fmn = s_mn[16];
        float span = s_mx[16] - fmn;
        float scale = (span > 0.f) ? (1023.0f / span) : 0.f;
        int bucket = min((int)((h - fmn) * scale), 1023);   // order-preserving
        int off_in = atomicAdd(&s_hist[bucket], 1);
        __syncthreads();                                    // B3

        // inclusive scan of bucket sizes
        f = s_hist[t];
#pragma unroll
        for (int d2 = 1; d2 < 64; d2 <<= 1) {
            int v = __shfl_up(f, d2);
            if (lane >= d2) f += v;
        }
        if (lane == 63) s_wsum[w] = f;
        __syncthreads();                                    // B4
        if (t == 0) {
            int run = 0;
#pragma unroll
            for (int k = 0; k < 16; ++k) { int tmp = s_wsum[k]; s_wsum[k] = run; run += tmp; }
        }
        __syncthreads();                                    // B5
        s_scan[t] = f + s_wsum[w];
        __syncthreads();                                    // B6

        int bs = s_scan[bucket] - s_hist[bucket];
        int be = s_scan[bucket];
        s_grp[bs + off_in] = h;
        __syncthreads();                                    // B7

        int c = bs;                 // lower buckets strictly less (monotone map)
        for (int k = bs; k < be; ++k) c += (s_grp[k] < h);
        s_flag[c] = 1;              // class start (same class -> same c)
        s_hist[t] = 0;              // re-zero for next iter
        __syncthreads();                                    // B8

        // inclusive scan of class-start flags -> dense rank
        int f2 = s_flag[t];
#pragma unroll
        for (int d2 = 1; d2 < 64; d2 <<= 1) {
            int v = __shfl_up(f2, d2);
            if (lane >= d2) f2 += v;
        }
        if (lane == 63) s_wsum[w] = f2;
        __syncthreads();                                    // B9
        if (t == 0) {
            int run = 0;
#pragma unroll
            for (int k = 0; k < 16; ++k) { int tmp = s_wsum[k]; s_wsum[k] = run; run += tmp; }
        }
        __syncthreads();                                    // B10
        s_scan[t] = f2 + s_wsum[w];
        s_flag[t] = 0;              // own flag consumed above
        __syncthreads();                                    // B11

        int rank = s_scan[c] - 1;
        s_lab[t] = rank;
        atomicAdd(&s_feats[rank], 1u);
        __syncthreads();                                    // B12
    }

    // feats out + fused diag[b] = dot(f_b, f_b) (int exact)
    unsigned int fv = s_feats[t];
    feats[(size_t)b * N + t] = fv;
    int sq = (int)(fv * fv);
#pragma unroll
    for (int o = 32; o > 0; o >>= 1) sq += __shfl_down(sq, o);
    if (lane == 0) s_wsum[w] = sq;
    __syncthreads();
    if (t == 0) {
        int tot = 0;
#pragma unroll
        for (int k = 0; k < 16; ++k) tot += s_wsum[k];
        diag[b] = (float)tot;
    }
}

// gram+normalize fused: one block per row i; f_i staged in LDS; writes
// normalized kernel value straight to d_out. int dots exact (< 2^31).
__global__ void __launch_bounds__(256) gram_k(const unsigned int* __restrict__ feats,
                                              const float* __restrict__ diag,
                                              float* __restrict__ out) {
    __shared__ unsigned int s_fi[N];
    int i = blockIdx.x, t = threadIdx.x;
    int lane = t & 63, w = t >> 6;
    ((uint4*)s_fi)[t] = ((const uint4*)(feats + (size_t)i * N))[t];
    __syncthreads();
    float di = diag[i];
    for (int jj = 0; jj < 16; ++jj) {
        int j = w * 16 + jj;
        const uint4* fj = (const uint4*)(feats + (size_t)j * N);
        const uint4* fi = (const uint4*)s_fi;
        int s = 0;
#pragma unroll
        for (int k = 0; k < 4; ++k) {
            uint4 vb = fj[lane + k * 64];
            uint4 va = fi[lane + k * 64];
            s += (int)(va.x * vb.x) + (int)(va.y * vb.y)
               + (int)(va.z * vb.z) + (int)(va.w * vb.w);
        }
#pragma unroll
        for (int off = 32; off > 0; off >>= 1) s += __shfl_down(s, off);
        if (lane == 0) out[i * B + j] = (float)s / sqrtf(di * diag[j]);
    }
}

extern "C" void kernel_launch(void* const* d_in, const int* in_sizes, int n_in,
                              void* d_out, int out_size, void* d_ws, size_t ws_size,
                              hipStream_t stream) {
    const int*   esrc = (const int*)d_in[0];
    const int*   edst = (const int*)d_in[1];
    const int*   lab0 = (const int*)d_in[2];
    const float* hw   = (const float*)d_in[3];

    char* ws = (char*)d_ws;
    unsigned int* adj   = (unsigned int*)(ws + ADJ_OFF);
    unsigned int* feats = (unsigned int*)(ws + FEATS_OFF);
    float*        diag  = (float*)(ws + DIAG_OFF);

    build_adj_k<<<B * 2, 1024, 0, stream>>>(esrc, edst, adj);
    wl_mega_k<<<B, 1024, 0, stream>>>(adj, lab0, hw, feats, diag);
    gram_k<<<B, 256, 0, stream>>>(feats, diag, (float*)d_out);
}

// Round 12
// 119.911 us; speedup vs baseline: 1.1954x; 1.0205x over previous
//
#include <hip/hip_runtime.h>

#define B 64
#define N 1024
#define E 16384
#define WPR 32          // words per adjacency row = N/32
#define NITER 5
#define CSR_SLOTS (E + N)   // even-aligned per-node alloc: <=1 pad slot/node

// ---- workspace layout (bytes) ---- (NO memset: every region fully stored
// before any read; harness 0xAA poison harmless)
#define ADJ_OFF   0
#define ADJ_BYTES ((size_t)B * N * WPR * 4)
#define FEATS_OFF ADJ_BYTES
#define DIAG_OFF  (FEATS_OFF + (size_t)B * N * 4)

// Bit adjacency built in LDS, full rows STORED to global (stores-only => safe
// against workspace poison). R5-R11 measured ~9us.
__global__ void __launch_bounds__(1024) build_adj_k(const int* __restrict__ src,
                                                    const int* __restrict__ dst,
                                                    unsigned int* __restrict__ adj) {
    __shared__ unsigned int s_adj[512 * WPR];       // 64 KiB: 512 rows
    int t = threadIdx.x;
    int b = blockIdx.x >> 1;
    int half = blockIdx.x & 1;
    int row_base = half << 9;

    uint4* s4 = (uint4*)s_adj;
#pragma unroll
    for (int k = 0; k < 4; ++k) s4[t + k * 1024] = make_uint4(0, 0, 0, 0);
    __syncthreads();

    const int* sg = src + (size_t)b * E;
    const int* dg = dst + (size_t)b * E;
#pragma unroll
    for (int k = 0; k < 16; ++k) {
        int e = t + k * 1024;
        int s = sg[e];
        int d = dg[e];
        int r = s - row_base;
        if ((unsigned)r < 512u)
            atomicOr(&s_adj[r * WPR + (d >> 5)], 1u << (d & 31));  // idempotent dedup
    }
    __syncthreads();

    uint4* g4 = (uint4*)(adj + ((size_t)b * N + row_base) * WPR);
#pragma unroll
    for (int k = 0; k < 4; ++k) g4[t + k * 1024] = s4[t + k * 1024];
}

// Whole WL loop, one block per graph, LDS-resident. R12 = R11 (measured-best
// R7 rank machinery + pair-packed gather) + NO-TIE FAST PATH: when all keys
// are distinct (generic after iter 1), rank_i = c_i directly -> skip both
// flag-scans (12 -> 9 barriers) and use conflict-free non-atomic bincount.
// Tie detection piggybacks on the within-bucket count (eq>1 -> flag); the
// flag sentinel is (it+1) so stale values self-invalidate without a reset
// barrier. Tie iterations fall back to the proven R11 scan path (+1 barrier).
__global__ void __launch_bounds__(1024) wl_mega_k(const unsigned int* __restrict__ adj,
                                                  const int* __restrict__ lab0,
                                                  const float* __restrict__ hw,
                                                  unsigned int* __restrict__ feats,
                                                  float* __restrict__ diag) {
    __shared__ unsigned short s_nbr[CSR_SLOTS];     // 34 KB even-aligned CSR
    __shared__ int s_lab[N + 2];                    // +sentinel slot (=0)
    __shared__ int s_hist[N];
    __shared__ int s_scan[N];
    __shared__ float s_grp[N];
    __shared__ int s_flag[N];
    __shared__ unsigned int s_feats[N];
    __shared__ int s_wsum[16];
    __shared__ float s_mn[17], s_mx[17];
    __shared__ int s_K;
    __shared__ int s_anytie;
    int b = blockIdx.x, t = threadIdx.x;
    int lane = t & 63, w = t >> 6;

    // ---- Phase A: row -> deg/CSR/K, init labels + bincount ----
    uint4 r[8];
    const uint4* rowg = (const uint4*)(adj + ((size_t)b * N + t) * WPR);
#pragma unroll
    for (int k = 0; k < 8; ++k) r[k] = rowg[k];
    int dg = 0;
#pragma unroll
    for (int k = 0; k < 8; ++k)
        dg += __popc(r[k].x) + __popc(r[k].y) + __popc(r[k].z) + __popc(r[k].w);
    int alloc = (dg + 1) & ~1;                      // even per-node CSR alloc

    // wave inclusive scan of alloc + wave max of deg
    int f = alloc;
#pragma unroll
    for (int d2 = 1; d2 < 64; d2 <<= 1) {
        int v = __shfl_up(f, d2);
        if (lane >= d2) f += v;
    }
    int km = dg;
#pragma unroll
    for (int o = 32; o > 0; o >>= 1) km = max(km, __shfl_down(km, o));
    if (lane == 63) s_wsum[w] = f;
    if (lane == 0)  s_scan[w] = km;                 // scratch for K partials

    int l0 = lab0[(size_t)b * N + t];
    s_lab[t] = l0;
    s_feats[t] = 0;
    s_hist[t] = 0;
    s_flag[t] = 0;
    if (t == 0) { s_lab[N] = 0; s_anytie = 0; }     // sentinel label + tie flag
    __syncthreads();                                        // A1
    if (t == 0) {                                   // serial combine (R7-style)
        int run = 0, m = 0;
#pragma unroll
        for (int k = 0; k < 16; ++k) {
            int tmp = s_wsum[k]; s_wsum[k] = run; run += tmp;
            m = max(m, s_scan[k]);
        }
        s_K = m;
    }
    // init label bincount (labels < 16) via ballot
#pragma unroll
    for (int v = 0; v < 16; ++v) {
        unsigned long long m = __ballot(l0 == v);
        if (lane == v) {
            int c = __popcll(m);
            if (c) atomicAdd(&s_feats[v], (unsigned)c);
        }
    }
    __syncthreads();                                        // A2
    int start = (f - alloc) + s_wsum[w];            // even => u32-aligned

    // pack own row's set bits ONCE -> u16 list; pad odd deg with sentinel N
    {
        int idx = start;
#pragma unroll
        for (int k = 0; k < 8; ++k) {
            unsigned int wv[4] = { r[k].x, r[k].y, r[k].z, r[k].w };
#pragma unroll
            for (int c2 = 0; c2 < 4; ++c2) {
                unsigned int word = wv[c2];
                int bb = (k * 4 + c2) << 5;
                while (word) {
                    int j = __ffs(word) - 1;
                    word &= word - 1;
                    s_nbr[idx++] = (unsigned short)(bb + j);
                }
            }
        }
        if (dg & 1) s_nbr[idx] = (unsigned short)N; // sentinel -> adds 0
    }
    float Kf = (float)s_K;
    float w0 = hw[0], w1 = hw[1];
    int pairs = alloc >> 1;
    int pstart = start >> 1;
    __syncthreads();                                        // A3

    // ---- Phase B: 5 WL iterations ----
    for (int it = 0; it < NITER; ++it) {
        // seg gather as u32 PAIRS (halved LDS ops) + exact-_rn hash (== numpy)
        int s = 0;
        const unsigned int* nbr32 = (const unsigned int*)s_nbr;
        for (int k = 0; k < pairs; ++k) {
            unsigned int pr = nbr32[pstart + k];
            s += s_lab[pr & 0xFFFFu] + s_lab[pr >> 16];
        }
        float t1 = __fmul_rn(__fmul_rn(Kf, w0), (float)s_lab[t]);
        float t2 = __fmul_rn(w1, __fsub_rn(__fadd_rn((float)s, (float)dg), Kf));
        float h  = __fadd_rn(t1, t2);

        // block min/max
        float mn = h, mx = h;
#pragma unroll
        for (int o = 32; o > 0; o >>= 1) {
            mn = fminf(mn, __shfl_down(mn, o));
            mx = fmaxf(mx, __shfl_down(mx, o));
        }
        if (lane == 0) { s_mn[w] = mn; s_mx[w] = mx; }
        __syncthreads();                                    // B1
        if (t == 0) {
            float a = s_mn[0], c = s_mx[0];
#pragma unroll
            for (int k = 1; k < 16; ++k) { a = fminf(a, s_mn[k]); c = fmaxf(c, s_mx[k]); }
            s_mn[16] = a; s_mx[16] = c;
        }
        __syncthreads();                                    // B2
        float fmn = s_mn[16];
        float span = s_mx[16] - fmn;
        float scale = (span > 0.f) ? (1023.0f / span) : 0.f;
        int bucket = min((int)((h - fmn) * scale), 1023);   // order-preserving
        int off_in = atomicAdd(&s_hist[bucket], 1);
        __syncthreads();                                    // B3

        // inclusive scan of bucket sizes
        f = s_hist[t];
#pragma unroll
        for (int d2 = 1; d2 < 64; d2 <<= 1) {
            int v = __shfl_up(f, d2);
            if (lane >= d2) f += v;
        }
        if (lane == 63) s_wsum[w] = f;
        __syncthreads();                                    // B4
        if (t == 0) {
            int run = 0;
#pragma unroll
            for (int k = 0; k < 16; ++k) { int tmp = s_wsum[k]; s_wsum[k] = run; run += tmp; }
        }
        __syncthreads();                                    // B5
        s_scan[t] = f + s_wsum[w];
        __syncthreads();                                    // B6

        int bs = s_scan[bucket] - s_hist[bucket];
        int be = s_scan[bucket];
        s_grp[bs + off_in] = h;
        __syncthreads();                                    // B7

        // within-bucket: c = strictly-less count, eq = equality count (incl self)
        int c = bs;                 // lower buckets strictly less (monotone map)
        int eq = 0;
        for (int k = bs; k < be; ++k) {
            float g = s_grp[k];
            c += (g < h);
            eq += (g == h);
        }
        if (eq > 1) s_anytie = it + 1;  // sentinel: stale iters self-invalidate
        s_hist[t] = 0;                  // re-zero for next iter
        __syncthreads();                                    // B8

        int rank;
        if (s_anytie != it + 1) {
            // FAST PATH: all keys distinct -> c is already the dense rank;
            // ranks form a permutation -> conflict-free non-atomic bincount.
            rank = c;
            s_lab[t] = rank;
            s_feats[rank] += 1u;
        } else {
            // TIE PATH (proven R11 machinery): class-start flags + scan
            s_flag[c] = 1;              // same class -> same c (benign race)
            __syncthreads();                                // T1
            int f2 = s_flag[t];
#pragma unroll
            for (int d2 = 1; d2 < 64; d2 <<= 1) {
                int v = __shfl_up(f2, d2);
                if (lane >= d2) f2 += v;
            }
            if (lane == 63) s_wsum[w] = f2;
            __syncthreads();                                // T2
            if (t == 0) {
                int run = 0;
#pragma unroll
                for (int k = 0; k < 16; ++k) { int tmp = s_wsum[k]; s_wsum[k] = run; run += tmp; }
            }
            __syncthreads();                                // T3
            s_scan[t] = f2 + s_wsum[w];
            s_flag[t] = 0;              // own flag consumed above
            __syncthreads();                                // T4
            rank = s_scan[c] - 1;
            s_lab[t] = rank;
            atomicAdd(&s_feats[rank], 1u);
        }
        __syncthreads();                                    // B9 (final)
    }

    // feats out + fused diag[b] = dot(f_b, f_b) (int exact)
    unsigned int fv = s_feats[t];
    feats[(size_t)b * N + t] = fv;
    int sq = (int)(fv * fv);
#pragma unroll
    for (int o = 32; o > 0; o >>= 1) sq += __shfl_down(sq, o);
    if (lane == 0) s_wsum[w] = sq;
    __syncthreads();
    if (t == 0) {
        int tot = 0;
#pragma unroll
        for (int k = 0; k < 16; ++k) tot += s_wsum[k];
        diag[b] = (float)tot;
    }
}

// gram+normalize fused: one block per row i; f_i staged in LDS; writes
// normalized kernel value straight to d_out. int dots exact (< 2^31).
__global__ void __launch_bounds__(256) gram_k(const unsigned int* __restrict__ feats,
                                              const float* __restrict__ diag,
                                              float* __restrict__ out) {
    __shared__ unsigned int s_fi[N];
    int i = blockIdx.x, t = threadIdx.x;
    int lane = t & 63, w = t >> 6;
    ((uint4*)s_fi)[t] = ((const uint4*)(feats + (size_t)i * N))[t];
    __syncthreads();
    float di = diag[i];
    for (int jj = 0; jj < 16; ++jj) {
        int j = w * 16 + jj;
        const uint4* fj = (const uint4*)(feats + (size_t)j * N);
        const uint4* fi = (const uint4*)s_fi;
        int s = 0;
#pragma unroll
        for (int k = 0; k < 4; ++k) {
            uint4 vb = fj[lane + k * 64];
            uint4 va = fi[lane + k * 64];
            s += (int)(va.x * vb.x) + (int)(va.y * vb.y)
               + (int)(va.z * vb.z) + (int)(va.w * vb.w);
        }
#pragma unroll
        for (int off = 32; off > 0; off >>= 1) s += __shfl_down(s, off);
        if (lane == 0) out[i * B + j] = (float)s / sqrtf(di * diag[j]);
    }
}

extern "C" void kernel_launch(void* const* d_in, const int* in_sizes, int n_in,
                              void* d_out, int out_size, void* d_ws, size_t ws_size,
                              hipStream_t stream) {
    const int*   esrc = (const int*)d_in[0];
    const int*   edst = (const int*)d_in[1];
    const int*   lab0 = (const int*)d_in[2];
    const float* hw   = (const float*)d_in[3];

    char* ws = (char*)d_ws;
    unsigned int* adj   = (unsigned int*)(ws + ADJ_OFF);
    unsigned int* feats = (unsigned int*)(ws + FEATS_OFF);
    float*        diag  = (float*)(ws + DIAG_OFF);

    build_adj_k<<<B * 2, 1024, 0, stream>>>(esrc, edst, adj);
    wl_mega_k<<<B, 1024, 0, stream>>>(adj, lab0, hw, feats, diag);
    gram_k<<<B, 256, 0, stream>>>(feats, diag, (float*)d_out);
}